// Round 1
// baseline (236.164 us; speedup 1.0000x reference)
//
#include <hip/hip_runtime.h>

#define D 4096
#define RPB 4   // rows per block: grid = 8192/4 = 2048 -> 8 blocks/CU, all resident

// In-register 16-point Walsh-Hadamard (order-agnostic: H16 over any 4 index bits).
__device__ __forceinline__ void fwht16(float v[16]) {
#pragma unroll
    for (int s = 1; s < 16; s <<= 1) {
#pragma unroll
        for (int i = 0; i < 16; i++) {
            if (!(i & s)) {
                float a = v[i], b = v[i ^ s];
                v[i]     = a + b;
                v[i ^ s] = a - b;
            }
        }
    }
}

// Raw barrier that does NOT drain vmcnt: prefetch loads stay in flight across it.
// lgkmcnt(0) makes this wave's LDS writes visible before the barrier.
__device__ __forceinline__ void lds_barrier() {
    asm volatile("s_waitcnt lgkmcnt(0)" ::: "memory");
    __builtin_amdgcn_s_barrier();
}

// Bit-partition of element index e[11:0]:
//   P1 (registers): bits {11,10,1,0}  -> load  v[4k+j] = x[row*D + k*1024 + 4t + j]
//                                        (each dwordx4 instr = 1 KB contiguous per wave)
//   P2 (registers): bits {5,4,3,2}    -> identical stride-17 LDS code as before
//   P3 (registers): bits {9,8,7,6}    -> stores: 64 lanes x 4B = 256 B contiguous/instr
// LDS slot f = 17*T + Q with T = e[9:2] (the P1 thread id), Q = (e[11:10]<<2)|e[1:0].
// Stride-17 pad keeps all phases at <=2-3-way bank aliasing (2-way is free).
__global__ __launch_bounds__(256, 6) void fwht_kernel(const float* __restrict__ x,
                                                      const float* __restrict__ signs,
                                                      float* __restrict__ out) {
    __shared__ float lds[4352];  // 4096 + 256 pad = 17 KB -> 9 blocks/CU by LDS

    const int t = threadIdx.x;
    const long row0 = (long)blockIdx.x * RPB;

    // Signs live in registers for all RPB rows (16 KB buffer, loaded once).
    float s[16];
    {
        const float4* __restrict__ sv = (const float4*)signs;
#pragma unroll
        for (int k = 0; k < 4; k++) {
            float4 g = sv[k * 256 + t];
            s[4 * k + 0] = g.x; s[4 * k + 1] = g.y;
            s[4 * k + 2] = g.z; s[4 * k + 3] = g.w;
        }
    }

    float v[16], u[16];

    // Load row0 (coalesced: lane i of a wave reads bytes [16i,16i+16) of a 1 KB span).
    {
        const float4* __restrict__ xv = (const float4*)(x + row0 * (long)D);
#pragma unroll
        for (int k = 0; k < 4; k++) {
            float4 a = xv[k * 256 + t];
            v[4 * k + 0] = a.x * s[4 * k + 0];
            v[4 * k + 1] = a.y * s[4 * k + 1];
            v[4 * k + 2] = a.z * s[4 * k + 2];
            v[4 * k + 3] = a.w * s[4 * k + 3];
        }
    }

    // Phase-invariant LDS addressing.
    const int a2    = t >> 4, bb = t & 15;
    const int base2 = a2 * 272 + bb;                          // P2: f = base2 + a1*17
    const int p3    = (t >> 2) & 15;
    const int base3 = 17 * p3 + ((t >> 6) << 2) + (t & 3);    // P3: f = base3 + c*272
    const int outoff = (t >> 6) * 1024 + (t & 63);            // e = outoff + c*64

    for (int i = 0; i < RPB; i++) {
        // ---- P1: H16 over bits {11,10,1,0}; contiguous padded LDS write ----
        fwht16(v);
#pragma unroll
        for (int q = 0; q < 16; q++) lds[17 * t + q] = v[q];

        // Prefetch next row into u BEFORE the barrier; raw s_barrier keeps these
        // 4 dwordx4 loads in flight underneath P2+P3 (~>1500 cyc of LDS/VALU work).
        if (i + 1 < RPB) {
            const float4* __restrict__ xv =
                (const float4*)(x + (row0 + i + 1) * (long)D);
#pragma unroll
            for (int k = 0; k < 4; k++) {
                float4 a = xv[k * 256 + t];
                u[4 * k + 0] = a.x; u[4 * k + 1] = a.y;
                u[4 * k + 2] = a.z; u[4 * k + 3] = a.w;
            }
        }

        lds_barrier();

        // ---- P2: gather stride 17, H16 over bits {5,4,3,2}, write back ----
#pragma unroll
        for (int a1 = 0; a1 < 16; a1++) v[a1] = lds[base2 + a1 * 17];
        fwht16(v);
#pragma unroll
        for (int a1 = 0; a1 < 16; a1++) lds[base2 + a1 * 17] = v[a1];

        lds_barrier();

        // ---- P3: gather stride 272, H16 over bits {9,8,7,6}, coalesced store ----
#pragma unroll
        for (int c = 0; c < 16; c++) v[c] = lds[base3 + c * 272];
        fwht16(v);
        {
            const float scale = 1.0f / 64.0f;  // 4096^-0.5
            float* __restrict__ orow = out + (row0 + i) * (long)D + outoff;
#pragma unroll
            for (int c = 0; c < 16; c++) orow[c * 64] = v[c] * scale;
        }

        if (i + 1 < RPB) {
            // P3 reads were consumed before each wave reaches this barrier, so after
            // it the next iteration's P1 writes cannot race them. No lgkm wait needed.
            __builtin_amdgcn_s_barrier();
#pragma unroll
            for (int q = 0; q < 16; q++) v[q] = u[q] * s[q];  // waits vmcnt here (late)
        }
    }
}

extern "C" void kernel_launch(void* const* d_in, const int* in_sizes, int n_in,
                              void* d_out, int out_size, void* d_ws, size_t ws_size,
                              hipStream_t stream) {
    const float* x = (const float*)d_in[0];
    const float* signs = (const float*)d_in[1];
    float* out = (float*)d_out;
    const int rows = in_sizes[0] / D;  // 8192
    fwht_kernel<<<dim3(rows / RPB), dim3(256), 0, stream>>>(x, signs, out);
}

// Round 2
// 228.805 us; speedup vs baseline: 1.0322x; 1.0322x over previous
//
#include <hip/hip_runtime.h>

#define D 4096

// In-register 16-point Walsh-Hadamard (order-agnostic: H16 over any 4 index bits).
__device__ __forceinline__ void fwht16(float v[16]) {
#pragma unroll
    for (int s = 1; s < 16; s <<= 1) {
#pragma unroll
        for (int i = 0; i < 16; i++) {
            if (!(i & s)) {
                float a = v[i], b = v[i ^ s];
                v[i]     = a + b;
                v[i ^ s] = a - b;
            }
        }
    }
}

// One block per row (8192 blocks -> max inter-block TLP; RPB pipelining measured
// SLOWER in round 1: 88 vs ~68.6 us).
//
// Bit-partition of element index e[11:0]:
//   P1 (registers): bits {11,10,1,0} -> load instr k: lane reads 16B at
//                   1024k + 16*lane -> each wave-instr = 1 KB fully contiguous
//                   (16 cache lines, 100% line utilization; old layout touched
//                   64 lines/instr at 25% utilization -> 4x TA traffic).
//   P2 (registers): bits {5,4,3,2}
//   P3 (registers): bits {9,8,7,6}
//
// LDS layout: f = 273*e[9:6] + 17*e[5:2] + q,  q = (e[11:10]<<2)|e[1:0].
// Double pad (17 per 16 elems, +1 per 256): 273 % 32 = 17 (odd) so the P2/P3
// A-stride gathers spread across all banks (~2-way aliasing = free), unlike the
// old 272-stride (272 % 32 = 16 -> 8 lanes/bank).
__global__ __launch_bounds__(256) void fwht_kernel(const float* __restrict__ x,
                                                   const float* __restrict__ signs,
                                                   float* __restrict__ out) {
    __shared__ float lds[4368];  // max f = 273*15+17*15+15 = 4365; 17.1 KB

    const int t = threadIdx.x;
    const long row = blockIdx.x;

    float v[16];

    // ---- P1: coalesced 1KB-per-instr load, apply signs, H16 over {0,1,10,11} ----
    {
        const float4* __restrict__ xv = (const float4*)(x + row * (long)D);
        const float4* __restrict__ sv = (const float4*)signs;
#pragma unroll
        for (int k = 0; k < 4; k++) {
            float4 a = xv[k * 256 + t];   // e = 1024k + 4t + j
            float4 s = sv[k * 256 + t];
            v[4 * k + 0] = a.x * s.x;
            v[4 * k + 1] = a.y * s.y;
            v[4 * k + 2] = a.z * s.z;
            v[4 * k + 3] = a.w * s.w;
        }
    }
    fwht16(v);

    // contiguous padded write: t = e[9:2], f = 17t + (t>>4) + q -> 4x ds_write_b128
    {
        const int wbase = 17 * t + (t >> 4);
#pragma unroll
        for (int q = 0; q < 16; q++) lds[wbase + q] = v[q];
    }
    __syncthreads();

    // ---- P2: thread (A = t>>4, q = t&15) gathers over B = e[5:2], stride 17 ----
    {
        const int base = 273 * (t >> 4) + (t & 15);
#pragma unroll
        for (int B = 0; B < 16; B++) v[B] = lds[base + 17 * B];
        fwht16(v);
#pragma unroll
        for (int B = 0; B < 16; B++) lds[base + 17 * B] = v[B];
    }
    __syncthreads();

    // ---- P3: thread (q = t>>4, B = t&15) gathers over A = e[9:6], stride 273 ----
    {
        const int base = 17 * (t & 15) + (t >> 4);
        float u[16];
#pragma unroll
        for (int A = 0; A < 16; A++) u[A] = lds[base + 273 * A];
        fwht16(u);
        const float scale = 1.0f / 64.0f;  // 4096^-0.5
        // e = (q>>2)*1024 + A*64 + B*4 + (q&3); per instr (fixed A) a wave writes
        // 64 consecutive floats = 256 B contiguous. Nontemporal: output is never
        // re-read; keep L2/L3 capacity for the input stream.
        float* __restrict__ orow = out + row * (long)D
                                 + ((t >> 6) * 1024) + ((t & 15) * 4) + ((t >> 4) & 3);
#pragma unroll
        for (int A = 0; A < 16; A++)
            __builtin_nontemporal_store(u[A] * scale, orow + A * 64);
    }
}

extern "C" void kernel_launch(void* const* d_in, const int* in_sizes, int n_in,
                              void* d_out, int out_size, void* d_ws, size_t ws_size,
                              hipStream_t stream) {
    const float* x = (const float*)d_in[0];
    const float* signs = (const float*)d_in[1];
    float* out = (float*)d_out;
    const int rows = in_sizes[0] / D;  // 8192
    fwht_kernel<<<dim3(rows), dim3(256), 0, stream>>>(x, signs, out);
}